// Round 1
// 229.908 us; speedup vs baseline: 1.0268x; 1.0268x over previous
//
#include <hip/hip_runtime.h>

#define HWPIX 16384
#define XSTR 200   // lx stride in shorts (100 words); per-wave quarter also hosts lh
#define HSTR 104   // lh stride in shorts (52 words)

typedef float f32x4 __attribute__((ext_vector_type(4)));
typedef short s16x8 __attribute__((ext_vector_type(8)));

static __device__ __forceinline__ unsigned short f2bf(float f) {
    unsigned int u = __builtin_bit_cast(unsigned int, f);
    u += 0x7fffu + ((u >> 16) & 1u);
    return (unsigned short)(u >> 16);
}
static __device__ __forceinline__ unsigned int pack2(float lo, float hi) {
    return (unsigned int)f2bf(lo) | ((unsigned int)f2bf(hi) << 16);
}

// async global->LDS, 16B per lane. LDS dest is wave-uniform base + lane*16.
static __device__ __forceinline__ void gll16(const void* g, void* l) {
    __builtin_amdgcn_global_load_lds(
        (const __attribute__((address_space(1))) unsigned int*)g,
        (__attribute__((address_space(3))) unsigned int*)l,
        16, 0, 0);
}

// stage one 12-frag chunk (12288 B) from gsrc into lbuf; 12 wave-runs of 1024 B.
static __device__ __forceinline__ void stage_chunk(const unsigned short* gsrc,
                                                   unsigned short* lbuf,
                                                   int wv, int lane) {
    #pragma unroll
    for (int i = 0; i < 3; ++i) {
        int rr = wv * 3 + i;                       // wave-uniform run index
        gll16((const char*)gsrc + rr * 1024 + lane * 16,
              (char*)lbuf + rr * 1024);
    }
}

// ws layout: floats [0,1536) gmean, [1536,3072) xg, [3072,3168) s1l, [3168,3264) t1l,
// [3264,3456) s2l, [3456,3648) t2l. Byte 16384: W1 bf16 frags (36864 B), then W2 frags.

__global__ __launch_bounds__(256) void prep_kernel(
    const float* __restrict__ x1, const float* __restrict__ x2, const float* __restrict__ x3,
    const float* __restrict__ lw1, const float* __restrict__ lb1,
    const float* __restrict__ lg1, const float* __restrict__ lbe1,
    const float* __restrict__ lm1, const float* __restrict__ lv1,
    const float* __restrict__ lw2, const float* __restrict__ lb2,
    const float* __restrict__ lg2, const float* __restrict__ lbe2,
    const float* __restrict__ lm2, const float* __restrict__ lv2,
    float* __restrict__ wsf, unsigned short* __restrict__ w1f, unsigned short* __restrict__ w2f)
{
    const int bid = blockIdx.x, t = threadIdx.x;
    if (bid < 1536) {
        // GAP over one (b, channel) fp32 plane: 16384 floats
        int b = bid / 192, c = bid % 192;
        int g = c >> 6, cc = c & 63;
        const float* base = (g == 0 ? x1 : (g == 1 ? x2 : x3)) + ((size_t)(b * 64 + cc)) * HWPIX;
        float s = 0.f;
        #pragma unroll
        for (int it = 0; it < 16; ++it) {
            f32x4 v = *(const f32x4*)(base + it * 1024 + t * 4);
            s += v[0] + v[1] + v[2] + v[3];
        }
        for (int off = 32; off > 0; off >>= 1) s += __shfl_down(s, off, 64);
        __shared__ float part[4];
        if ((t & 63) == 0) part[t >> 6] = s;
        __syncthreads();
        if (t == 0) wsf[bid] = (part[0] + part[1] + part[2] + part[3]) * (1.f / (float)HWPIX);
    } else if (bid == 1536) {
        if (t < 96) {
            float s = lg1[t] * __frsqrt_rn(lv1[t] + 1e-5f);
            wsf[3072 + t] = s;
            wsf[3168 + t] = (lb1[t] - lm1[t]) * s + lbe1[t];
        }
    } else if (bid == 1537) {
        if (t < 192) {
            float s = lg2[t] * __frsqrt_rn(lv2[t] + 1e-5f);
            wsf[3264 + t] = s;
            wsf[3456 + t] = (lb2[t] - lm2[t]) * s + lbe2[t];
        }
    } else if (bid < 1547) {
        // W1 pretile fp32 -> bf16 B-frags. frag f = kb*6+nb; lane l holds
        // B[k=(l>>4)*8+j][n=l&15] with B=W1^T -> W1[row=n][col=k..k+7]
        int slot = (bid - 1538) * 256 + t;          // [0, 2304)
        int f = slot >> 6, l = slot & 63;
        int kb = f / 6, nb = f % 6;
        int row = nb * 16 + (l & 15), col0 = kb * 32 + ((l >> 4) << 3);
        const float* src = lw1 + row * 192 + col0;
        f32x4 a = *(const f32x4*)src, b4 = *(const f32x4*)(src + 4);
        unsigned int* dst = (unsigned int*)(w1f + f * 512 + l * 8);
        dst[0] = pack2(a[0], a[1]); dst[1] = pack2(a[2], a[3]);
        dst[2] = pack2(b4[0], b4[1]); dst[3] = pack2(b4[2], b4[3]);
    } else {
        // W2 pretile: frag f = kb*12+nb; W2[row=n][col=k..k+7], rows 0..191, cols 0..95
        int slot = (bid - 1547) * 256 + t;
        int f = slot >> 6, l = slot & 63;
        int kb = f / 12, nb = f % 12;
        int row = nb * 16 + (l & 15), col0 = kb * 32 + ((l >> 4) << 3);
        const float* src = lw2 + row * 96 + col0;
        f32x4 a = *(const f32x4*)src, b4 = *(const f32x4*)(src + 4);
        unsigned int* dst = (unsigned int*)(w2f + f * 512 + l * 8);
        dst[0] = pack2(a[0], a[1]); dst[1] = pack2(a[2], a[3]);
        dst[2] = pack2(b4[0], b4[1]); dst[3] = pack2(b4[2], b4[3]);
    }
}

__global__ __launch_bounds__(256) void gpath_kernel(
    const float* __restrict__ gw1, const float* __restrict__ gb1,
    const float* __restrict__ gg1, const float* __restrict__ gbe1,
    const float* __restrict__ gm1, const float* __restrict__ gv1,
    const float* __restrict__ gw2, const float* __restrict__ gb2,
    const float* __restrict__ gg2, const float* __restrict__ gbe2,
    const float* __restrict__ gm2, const float* __restrict__ gv2,
    float* __restrict__ wsf)
{
    __shared__ float xbar[192], hbuf[96];
    const int b = blockIdx.x, t = threadIdx.x;
    if (t < 192) xbar[t] = wsf[b * 192 + t];
    __syncthreads();
    if (t < 96) {
        float acc = 0.f;
        for (int c = 0; c < 192; ++c) acc += gw1[t * 192 + c] * xbar[c];
        float s = gg1[t] * __frsqrt_rn(gv1[t] + 1e-5f);
        float tt = (gb1[t] - gm1[t]) * s + gbe1[t];
        hbuf[t] = fmaxf(acc * s + tt, 0.f);
    }
    __syncthreads();
    if (t < 192) {
        float acc = 0.f;
        for (int j = 0; j < 96; ++j) acc += gw2[t * 96 + j] * hbuf[j];
        float s = gg2[t] * __frsqrt_rn(gv2[t] + 1e-5f);
        float tt = (gb2[t] - gm2[t]) * s + gbe2[t];
        wsf[1536 + b * 192 + t] = acc * s + tt;
    }
}

// 64-pixel tiles, 2048 blocks. LDS = 25600 (lx, hosts lh per-wave) + 24576 (lw dbuf)
// + 3072 (lpar) = 53248 B -> 3 blocks/CU. 6 barriers; weight chunks staged one phase
// ahead via global_load_lds (async, drained by the next barrier's vmcnt wait).
__global__ __launch_bounds__(256, 3) void main_kernel(
    const float* __restrict__ x1, const float* __restrict__ x2, const float* __restrict__ x3,
    const float* __restrict__ wsf,
    const unsigned short* __restrict__ w1f, const unsigned short* __restrict__ w2f,
    float* __restrict__ out)
{
    __shared__ __align__(16) unsigned short lx[64 * XSTR];   // bf16 [pix][ch]; lh aliases
    __shared__ __align__(16) unsigned short lw[2][12 * 512]; // bf16 frag chunk double-buffer
    __shared__ float lpar[768];                              // s1 t1 | s2 t2 xg

    const int t = threadIdx.x;
    const int b = blockIdx.x >> 8;
    const int pix0 = (blockIdx.x & 255) << 6;
    const int lane = t & 63;
    const int wv = t >> 6;

    // issue W1 chunk0 (kb 0,1) immediately — covered by the whole lx staging phase
    stage_chunk(w1f, lw[0], wv, lane);

    if (t < 96)  { lpar[t] = wsf[3072 + t]; lpar[96 + t] = wsf[3168 + t]; }
    if (t < 192) {
        lpar[192 + t] = wsf[3264 + t];
        lpar[384 + t] = wsf[3456 + t];
        lpar[576 + t] = wsf[1536 + b * 192 + t];
    }
    // ---- X staging: fp32 global [ch][pix] -> bf16 LDS [pix][ch], pair-packed words
    {
        const int pq = t >> 4;        // pixel quad 0..15
        const int cb = t & 15;
        unsigned int* lx32 = (unsigned int*)lx;
        #pragma unroll
        for (int i = 0; i < 6; ++i) {
            int cp = i * 16 + cb;     // channel pair 0..95
            int c0 = cp * 2;
            int g = c0 >> 6, cc0 = c0 & 63;
            const float* pl = (g == 0 ? x1 : (g == 1 ? x2 : x3))
                + ((size_t)(b * 64 + cc0)) * HWPIX + pix0 + pq * 4;
            f32x4 va = *(const f32x4*)pl;
            f32x4 vb = *(const f32x4*)(pl + HWPIX);   // channel c0+1, same group
            #pragma unroll
            for (int j = 0; j < 4; ++j)
                lx32[(pq * 4 + j) * 100 + cp] = pack2(va[j], vb[j]);
        }
    }
    __syncthreads();                                   // S1: lx + W1c0 ready

    const int col = lane & 15;
    const int q = lane >> 4;
    const int pixw = wv * 16;   // each wave owns one 16-pixel m-block
    unsigned short* lhp = &lx[pixw * XSTR];  // per-wave lh region (1656 of 3200 shorts)

    stage_chunk(w1f + 12 * 512, lw[1], wv, lane);      // W1 chunk1 (kb 2,3)

    // ---- Phase 1: H = relu(bn1(X @ W1^T)), K=192, three 2-kb steps ----
    f32x4 acc1[6];
    #pragma unroll
    for (int nb = 0; nb < 6; ++nb) acc1[nb] = (f32x4){0.f, 0.f, 0.f, 0.f};

#define P1_STEP(BUF, KB0)                                                              \
    _Pragma("unroll")                                                                  \
    for (int kbl = 0; kbl < 2; ++kbl) {                                                \
        s16x8 a = *(const s16x8*)&lx[(pixw + col) * XSTR + (KB0 + kbl) * 32 + q * 8];  \
        _Pragma("unroll")                                                              \
        for (int nb = 0; nb < 6; ++nb) {                                               \
            s16x8 bfr = *(const s16x8*)&lw[BUF][(kbl * 6 + nb) * 512 + lane * 8];      \
            acc1[nb] = __builtin_amdgcn_mfma_f32_16x16x32_bf16(a, bfr, acc1[nb], 0, 0, 0); \
        }                                                                              \
    }

    P1_STEP(0, 0)                                      // kb 0,1
    __syncthreads();                                   // S2: W1c1 landed, lw[0] free
    stage_chunk(w1f + 24 * 512, lw[0], wv, lane);      // W1 chunk2 (kb 4,5)
    P1_STEP(1, 2)                                      // kb 2,3
    __syncthreads();                                   // S3: W1c2 landed, lw[1] free
    stage_chunk(w2f, lw[1], wv, lane);                 // W2 chunk0 (kb 0)
    P1_STEP(0, 4)                                      // kb 4,5

    // lh write into own lx quarter: all phase-1 ds_reads precede these in program
    // order (per-wave in-order DS pipe), and no other wave touches this quarter.
    #pragma unroll
    for (int nb = 0; nb < 6; ++nb) {
        int j = nb * 16 + col;
        float sj = lpar[j], tj = lpar[96 + j];
        #pragma unroll
        for (int r = 0; r < 4; ++r)
            lhp[(q * 4 + r) * HSTR + j] = f2bf(fmaxf(acc1[nb][r] * sj + tj, 0.f));
    }
    __syncthreads();                                   // S4: W2c0 landed, lw[0] free
    stage_chunk(w2f + 12 * 512, lw[0], wv, lane);      // W2 chunk1 (kb 1)

    // ---- Phase 2: XL = bn2(H @ W2^T), K=96, three 1-kb steps ----
    f32x4 acc2[12];
    #pragma unroll
    for (int nb = 0; nb < 12; ++nb) acc2[nb] = (f32x4){0.f, 0.f, 0.f, 0.f};

#define P2_STEP(BUF, KB)                                                               \
    {                                                                                  \
        s16x8 a = *(const s16x8*)&lhp[col * HSTR + (KB) * 32 + q * 8];                 \
        _Pragma("unroll")                                                              \
        for (int nb = 0; nb < 12; ++nb) {                                              \
            s16x8 bfr = *(const s16x8*)&lw[BUF][nb * 512 + lane * 8];                  \
            acc2[nb] = __builtin_amdgcn_mfma_f32_16x16x32_bf16(a, bfr, acc2[nb], 0, 0, 0); \
        }                                                                              \
    }

    P2_STEP(1, 0)                                      // kb 0
    __syncthreads();                                   // S5: W2c1 landed, lw[1] free
    stage_chunk(w2f + 24 * 512, lw[1], wv, lane);      // W2 chunk2 (kb 2)
    P2_STEP(0, 1)                                      // kb 1
    __syncthreads();                                   // S6: W2c2 landed
    P2_STEP(1, 2)                                      // kb 2

    // ---- Epilogue: sigmoid(xl+xg), softmax over 3 groups, fp32 weighted sum ----
    #pragma unroll
    for (int nb = 0; nb < 4; ++nb) {
        int cc = nb * 16 + col;   // output channel; triplet at nb, nb+4, nb+8
        float s0 = lpar[192 + cc],        t0 = lpar[384 + cc],        g0 = lpar[576 + cc];
        float s1v = lpar[192 + 64 + cc],  t1v = lpar[384 + 64 + cc],  g1 = lpar[576 + 64 + cc];
        float s2v = lpar[192 + 128 + cc], t2v = lpar[384 + 128 + cc], g2 = lpar[576 + 128 + cc];
        size_t po = ((size_t)(b * 64 + cc)) * HWPIX + pix0 + pixw + q * 4;
        f32x4 xa = *(const f32x4*)(x1 + po);
        f32x4 xb = *(const f32x4*)(x2 + po);
        f32x4 xc = *(const f32x4*)(x3 + po);
        f32x4 res;
        #pragma unroll
        for (int r = 0; r < 4; ++r) {
            float v0 = acc2[nb][r] * s0 + t0 + g0;
            float v1 = acc2[nb + 4][r] * s1v + t1v + g1;
            float v2 = acc2[nb + 8][r] * s2v + t2v + g2;
            float w0 = 1.f / (1.f + __expf(-v0));
            float w1 = 1.f / (1.f + __expf(-v1));
            float w2 = 1.f / (1.f + __expf(-v2));
            float mx = fmaxf(w0, fmaxf(w1, w2));
            float e0 = __expf(w0 - mx), e1 = __expf(w1 - mx), e2 = __expf(w2 - mx);
            res[r] = (e0 * xa[r] + e1 * xb[r] + e2 * xc[r]) / (e0 + e1 + e2);
        }
        *(f32x4*)(out + po) = res;
    }
}

extern "C" void kernel_launch(void* const* d_in, const int* in_sizes, int n_in,
                              void* d_out, int out_size, void* d_ws, size_t ws_size,
                              hipStream_t stream) {
    (void)in_sizes; (void)n_in; (void)out_size; (void)ws_size;
    const float* x1  = (const float*)d_in[0];
    const float* x2  = (const float*)d_in[1];
    const float* x3  = (const float*)d_in[2];
    const float* lw1 = (const float*)d_in[3];
    const float* lb1 = (const float*)d_in[4];
    const float* lg1 = (const float*)d_in[5];
    const float* lbe1= (const float*)d_in[6];
    const float* lm1 = (const float*)d_in[7];
    const float* lv1 = (const float*)d_in[8];
    const float* lw2 = (const float*)d_in[9];
    const float* lb2 = (const float*)d_in[10];
    const float* lg2 = (const float*)d_in[11];
    const float* lbe2= (const float*)d_in[12];
    const float* lm2 = (const float*)d_in[13];
    const float* lv2 = (const float*)d_in[14];
    const float* gw1 = (const float*)d_in[15];
    const float* gb1 = (const float*)d_in[16];
    const float* gg1 = (const float*)d_in[17];
    const float* gbe1= (const float*)d_in[18];
    const float* gm1 = (const float*)d_in[19];
    const float* gv1 = (const float*)d_in[20];
    const float* gw2 = (const float*)d_in[21];
    const float* gb2 = (const float*)d_in[22];
    const float* gg2 = (const float*)d_in[23];
    const float* gbe2= (const float*)d_in[24];
    const float* gm2 = (const float*)d_in[25];
    const float* gv2 = (const float*)d_in[26];

    float* wsf = (float*)d_ws;
    unsigned short* w1f = (unsigned short*)((char*)d_ws + 16384);
    unsigned short* w2f = w1f + 18432;   // 36864 bytes after w1f

    prep_kernel<<<1556, 256, 0, stream>>>(x1, x2, x3,
        lw1, lb1, lg1, lbe1, lm1, lv1, lw2, lb2, lg2, lbe2, lm2, lv2,
        wsf, w1f, w2f);
    gpath_kernel<<<8, 256, 0, stream>>>(
        gw1, gb1, gg1, gbe1, gm1, gv1, gw2, gb2, gg2, gbe2, gm2, gv2, wsf);
    main_kernel<<<2048, 256, 0, stream>>>(x1, x2, x3, wsf, w1f, w2f, (float*)d_out);
}

// Round 2
// 227.965 us; speedup vs baseline: 1.0356x; 1.0085x over previous
//
#include <hip/hip_runtime.h>

#define HWPIX 16384
#define XSTR 200   // lx stride in shorts (100 words); per-wave quarter also hosts lh
#define HSTR 104   // lh stride in shorts (52 words)
#define L2E 1.4426950408889634f

typedef float f32x4 __attribute__((ext_vector_type(4)));
typedef short s16x8 __attribute__((ext_vector_type(8)));

static __device__ __forceinline__ unsigned short f2bf(float f) {
    unsigned int u = __builtin_bit_cast(unsigned int, f);
    u += 0x7fffu + ((u >> 16) & 1u);
    return (unsigned short)(u >> 16);
}
static __device__ __forceinline__ unsigned int pack2(float lo, float hi) {
    return (unsigned int)f2bf(lo) | ((unsigned int)f2bf(hi) << 16);
}
// HW packed f32->bf16 (RNE), one instruction for two converts
static __device__ __forceinline__ unsigned int cvtpk(float lo, float hi) {
    unsigned int r;
    asm("v_cvt_pk_bf16_f32 %0, %1, %2" : "=v"(r) : "v"(lo), "v"(hi));
    return r;
}

// ws layout: floats [0,1536) gmean, [1536,3072) xg, [3072,3168) s1l, [3168,3264) t1l,
// [3264,3456) s2l, [3456,3648) t2l. Byte 16384: W1 bf16 frags (36864 B), then W2 frags.

__global__ __launch_bounds__(256) void prep_kernel(
    const float* __restrict__ x1, const float* __restrict__ x2, const float* __restrict__ x3,
    const float* __restrict__ lw1, const float* __restrict__ lb1,
    const float* __restrict__ lg1, const float* __restrict__ lbe1,
    const float* __restrict__ lm1, const float* __restrict__ lv1,
    const float* __restrict__ lw2, const float* __restrict__ lb2,
    const float* __restrict__ lg2, const float* __restrict__ lbe2,
    const float* __restrict__ lm2, const float* __restrict__ lv2,
    float* __restrict__ wsf, unsigned short* __restrict__ w1f, unsigned short* __restrict__ w2f)
{
    const int bid = blockIdx.x, t = threadIdx.x;
    if (bid < 1536) {
        // GAP over one (b, channel) fp32 plane: 16384 floats
        int b = bid / 192, c = bid % 192;
        int g = c >> 6, cc = c & 63;
        const float* base = (g == 0 ? x1 : (g == 1 ? x2 : x3)) + ((size_t)(b * 64 + cc)) * HWPIX;
        float s = 0.f;
        #pragma unroll
        for (int it = 0; it < 16; ++it) {
            f32x4 v = *(const f32x4*)(base + it * 1024 + t * 4);
            s += v[0] + v[1] + v[2] + v[3];
        }
        for (int off = 32; off > 0; off >>= 1) s += __shfl_down(s, off, 64);
        __shared__ float part[4];
        if ((t & 63) == 0) part[t >> 6] = s;
        __syncthreads();
        if (t == 0) wsf[bid] = (part[0] + part[1] + part[2] + part[3]) * (1.f / (float)HWPIX);
    } else if (bid == 1536) {
        if (t < 96) {
            float s = lg1[t] * __frsqrt_rn(lv1[t] + 1e-5f);
            wsf[3072 + t] = s;
            wsf[3168 + t] = (lb1[t] - lm1[t]) * s + lbe1[t];
        }
    } else if (bid == 1537) {
        if (t < 192) {
            float s = lg2[t] * __frsqrt_rn(lv2[t] + 1e-5f);
            wsf[3264 + t] = s;
            wsf[3456 + t] = (lb2[t] - lm2[t]) * s + lbe2[t];
        }
    } else if (bid < 1547) {
        // W1 pretile fp32 -> bf16 B-frags. frag f = kb*6+nb; lane l holds
        // B[k=(l>>4)*8+j][n=l&15] with B=W1^T -> W1[row=n][col=k..k+7]
        int slot = (bid - 1538) * 256 + t;          // [0, 2304)
        int f = slot >> 6, l = slot & 63;
        int kb = f / 6, nb = f % 6;
        int row = nb * 16 + (l & 15), col0 = kb * 32 + ((l >> 4) << 3);
        const float* src = lw1 + row * 192 + col0;
        f32x4 a = *(const f32x4*)src, b4 = *(const f32x4*)(src + 4);
        unsigned int* dst = (unsigned int*)(w1f + f * 512 + l * 8);
        dst[0] = pack2(a[0], a[1]); dst[1] = pack2(a[2], a[3]);
        dst[2] = pack2(b4[0], b4[1]); dst[3] = pack2(b4[2], b4[3]);
    } else {
        // W2 pretile: frag f = kb*12+nb; W2[row=n][col=k..k+7], rows 0..191, cols 0..95
        int slot = (bid - 1547) * 256 + t;
        int f = slot >> 6, l = slot & 63;
        int kb = f / 12, nb = f % 12;
        int row = nb * 16 + (l & 15), col0 = kb * 32 + ((l >> 4) << 3);
        const float* src = lw2 + row * 96 + col0;
        f32x4 a = *(const f32x4*)src, b4 = *(const f32x4*)(src + 4);
        unsigned int* dst = (unsigned int*)(w2f + f * 512 + l * 8);
        dst[0] = pack2(a[0], a[1]); dst[1] = pack2(a[2], a[3]);
        dst[2] = pack2(b4[0], b4[1]); dst[3] = pack2(b4[2], b4[3]);
    }
}

__global__ __launch_bounds__(256) void gpath_kernel(
    const float* __restrict__ gw1, const float* __restrict__ gb1,
    const float* __restrict__ gg1, const float* __restrict__ gbe1,
    const float* __restrict__ gm1, const float* __restrict__ gv1,
    const float* __restrict__ gw2, const float* __restrict__ gb2,
    const float* __restrict__ gg2, const float* __restrict__ gbe2,
    const float* __restrict__ gm2, const float* __restrict__ gv2,
    float* __restrict__ wsf)
{
    __shared__ float xbar[192], hbuf[96];
    const int b = blockIdx.x, t = threadIdx.x;
    if (t < 192) xbar[t] = wsf[b * 192 + t];
    __syncthreads();
    if (t < 96) {
        float acc = 0.f;
        for (int c = 0; c < 192; ++c) acc += gw1[t * 192 + c] * xbar[c];
        float s = gg1[t] * __frsqrt_rn(gv1[t] + 1e-5f);
        float tt = (gb1[t] - gm1[t]) * s + gbe1[t];
        hbuf[t] = fmaxf(acc * s + tt, 0.f);
    }
    __syncthreads();
    if (t < 192) {
        float acc = 0.f;
        for (int j = 0; j < 96; ++j) acc += gw2[t * 96 + j] * hbuf[j];
        float s = gg2[t] * __frsqrt_rn(gv2[t] + 1e-5f);
        float tt = (gb2[t] - gm2[t]) * s + gbe2[t];
        wsf[1536 + b * 192 + t] = acc * s + tt;
    }
}

// 64-pixel tiles, 2048 blocks. LDS = 25600 (lx, hosts lh per-wave) + 2304 (lpar)
// = 27904 B. Weights are read straight from the pre-tiled global frags (L2-resident,
// coalesced 1 KB runs per wave) -> ONE barrier total; every wave independent after it.
__global__ __launch_bounds__(256, 4) void main_kernel(
    const float* __restrict__ x1, const float* __restrict__ x2, const float* __restrict__ x3,
    const float* __restrict__ wsf,
    const unsigned short* __restrict__ w1f, const unsigned short* __restrict__ w2f,
    float* __restrict__ out)
{
    __shared__ __align__(16) unsigned short lx[64 * XSTR];   // bf16 [pix][ch]; lh aliases
    __shared__ float lpar[576];   // s1[96] t1[96] | A2[192] B2[192] (pre-scaled epilogue)

    const int t = threadIdx.x;
    const int b = blockIdx.x >> 8;
    const int pix0 = (blockIdx.x & 255) << 6;
    const int lane = t & 63;
    const int wv = t >> 6;

    if (t < 96)  { lpar[t] = wsf[3072 + t]; lpar[96 + t] = wsf[3168 + t]; }
    if (t < 192) {
        // fold BN2 scale/shift + xg + sigmoid's -log2e into two constants:
        // sigmoid(acc*s2 + t2 + xg) = rcp(1 + exp2(acc*A + B))
        float s2 = wsf[3264 + t], t2 = wsf[3456 + t], xg = wsf[1536 + b * 192 + t];
        lpar[192 + t] = -L2E * s2;
        lpar[384 + t] = -L2E * (t2 + xg);
    }
    // ---- X staging: fp32 global [ch][pix] -> bf16 LDS [pix][ch], pair-packed words
    {
        const int pq = t >> 4;        // pixel quad 0..15
        const int cb = t & 15;
        unsigned int* lx32 = (unsigned int*)lx;
        #pragma unroll
        for (int i = 0; i < 6; ++i) {
            int cp = i * 16 + cb;     // channel pair 0..95
            int c0 = cp * 2;
            int g = c0 >> 6, cc0 = c0 & 63;
            const float* pl = (g == 0 ? x1 : (g == 1 ? x2 : x3))
                + ((size_t)(b * 64 + cc0)) * HWPIX + pix0 + pq * 4;
            f32x4 va = *(const f32x4*)pl;
            f32x4 vb = *(const f32x4*)(pl + HWPIX);   // channel c0+1, same group
            #pragma unroll
            for (int j = 0; j < 4; ++j)
                lx32[(pq * 4 + j) * 100 + cp] = cvtpk(va[j], vb[j]);
        }
    }
    __syncthreads();   // the ONLY barrier: lx + lpar published

    const int col = lane & 15;
    const int q = lane >> 4;
    const int pixw = wv * 16;   // each wave owns one 16-pixel m-block
    unsigned short* lhp = &lx[pixw * XSTR];  // per-wave lh region (private to this wave)

    // ---- Phase 1: H = relu(bn1(X @ W1^T)), K=192; B-frags streamed from global ----
    f32x4 acc1[6];
    #pragma unroll
    for (int nb = 0; nb < 6; ++nb) acc1[nb] = (f32x4){0.f, 0.f, 0.f, 0.f};

    #pragma unroll
    for (int kb = 0; kb < 6; ++kb) {
        s16x8 a = *(const s16x8*)&lx[(pixw + col) * XSTR + kb * 32 + q * 8];
        const unsigned short* wp = w1f + (kb * 6) * 512 + lane * 8;
        #pragma unroll
        for (int nb = 0; nb < 6; ++nb) {
            s16x8 bfr = *(const s16x8*)(wp + nb * 512);
            acc1[nb] = __builtin_amdgcn_mfma_f32_16x16x32_bf16(a, bfr, acc1[nb], 0, 0, 0);
        }
    }

    // lh write into own lx quarter (wave-private; per-wave DS ordering suffices)
    #pragma unroll
    for (int nbp = 0; nbp < 3; ++nbp) {
        int j0 = (2 * nbp) * 16 + col, j1 = (2 * nbp + 1) * 16 + col;
        float s0 = lpar[j0], t0 = lpar[96 + j0];
        float s1v = lpar[j1], t1v = lpar[96 + j1];
        #pragma unroll
        for (int r = 0; r < 4; ++r) {
            float h0 = fmaxf(acc1[2 * nbp][r] * s0 + t0, 0.f);
            float h1 = fmaxf(acc1[2 * nbp + 1][r] * s1v + t1v, 0.f);
            unsigned int w = cvtpk(h0, h1);
            int rowo = (q * 4 + r) * HSTR;
            lhp[rowo + j0] = (unsigned short)w;
            lhp[rowo + j1] = (unsigned short)(w >> 16);
        }
    }

    // ---- Phase 2: XL = bn2(H @ W2^T), K=96; B-frags streamed from global ----
    f32x4 acc2[12];
    #pragma unroll
    for (int nb = 0; nb < 12; ++nb) acc2[nb] = (f32x4){0.f, 0.f, 0.f, 0.f};

    #pragma unroll
    for (int kb = 0; kb < 3; ++kb) {
        s16x8 a = *(const s16x8*)&lhp[col * HSTR + kb * 32 + q * 8];
        const unsigned short* wp = w2f + (kb * 12) * 512 + lane * 8;
        #pragma unroll
        for (int nb = 0; nb < 12; ++nb) {
            s16x8 bfr = *(const s16x8*)(wp + nb * 512);
            acc2[nb] = __builtin_amdgcn_mfma_f32_16x16x32_bf16(a, bfr, acc2[nb], 0, 0, 0);
        }
    }

    // ---- Epilogue: sigmoid via exp2+rcp (pre-scaled), softmax w/o max-sub,
    //      fp32 weighted sum with rcp instead of divide ----
    #pragma unroll
    for (int nb = 0; nb < 4; ++nb) {
        int cc = nb * 16 + col;   // output channel; triplet at nb, nb+4, nb+8
        float A0 = lpar[192 + cc],       B0 = lpar[384 + cc];
        float A1 = lpar[192 + 64 + cc],  B1 = lpar[384 + 64 + cc];
        float A2 = lpar[192 + 128 + cc], B2 = lpar[384 + 128 + cc];
        size_t po = ((size_t)(b * 64 + cc)) * HWPIX + pix0 + pixw + q * 4;
        f32x4 xa = *(const f32x4*)(x1 + po);
        f32x4 xb = *(const f32x4*)(x2 + po);
        f32x4 xc = *(const f32x4*)(x3 + po);
        f32x4 res;
        #pragma unroll
        for (int r = 0; r < 4; ++r) {
            // wi = sigmoid(vi) in (0,1)  ->  exp(wi) in (1,e): no max-sub needed
            float w0 = __builtin_amdgcn_rcpf(1.f + __builtin_amdgcn_exp2f(acc2[nb][r]     * A0 + B0));
            float w1 = __builtin_amdgcn_rcpf(1.f + __builtin_amdgcn_exp2f(acc2[nb + 4][r] * A1 + B1));
            float w2 = __builtin_amdgcn_rcpf(1.f + __builtin_amdgcn_exp2f(acc2[nb + 8][r] * A2 + B2));
            float e0 = __builtin_amdgcn_exp2f(w0 * L2E);
            float e1 = __builtin_amdgcn_exp2f(w1 * L2E);
            float e2 = __builtin_amdgcn_exp2f(w2 * L2E);
            float inv = __builtin_amdgcn_rcpf(e0 + e1 + e2);
            res[r] = (e0 * xa[r] + e1 * xb[r] + e2 * xc[r]) * inv;
        }
        *(f32x4*)(out + po) = res;
    }
}

extern "C" void kernel_launch(void* const* d_in, const int* in_sizes, int n_in,
                              void* d_out, int out_size, void* d_ws, size_t ws_size,
                              hipStream_t stream) {
    (void)in_sizes; (void)n_in; (void)out_size; (void)ws_size;
    const float* x1  = (const float*)d_in[0];
    const float* x2  = (const float*)d_in[1];
    const float* x3  = (const float*)d_in[2];
    const float* lw1 = (const float*)d_in[3];
    const float* lb1 = (const float*)d_in[4];
    const float* lg1 = (const float*)d_in[5];
    const float* lbe1= (const float*)d_in[6];
    const float* lm1 = (const float*)d_in[7];
    const float* lv1 = (const float*)d_in[8];
    const float* lw2 = (const float*)d_in[9];
    const float* lb2 = (const float*)d_in[10];
    const float* lg2 = (const float*)d_in[11];
    const float* lbe2= (const float*)d_in[12];
    const float* lm2 = (const float*)d_in[13];
    const float* lv2 = (const float*)d_in[14];
    const float* gw1 = (const float*)d_in[15];
    const float* gb1 = (const float*)d_in[16];
    const float* gg1 = (const float*)d_in[17];
    const float* gbe1= (const float*)d_in[18];
    const float* gm1 = (const float*)d_in[19];
    const float* gv1 = (const float*)d_in[20];
    const float* gw2 = (const float*)d_in[21];
    const float* gb2 = (const float*)d_in[22];
    const float* gg2 = (const float*)d_in[23];
    const float* gbe2= (const float*)d_in[24];
    const float* gm2 = (const float*)d_in[25];
    const float* gv2 = (const float*)d_in[26];

    float* wsf = (float*)d_ws;
    unsigned short* w1f = (unsigned short*)((char*)d_ws + 16384);
    unsigned short* w2f = w1f + 18432;   // 36864 bytes after w1f

    prep_kernel<<<1556, 256, 0, stream>>>(x1, x2, x3,
        lw1, lb1, lg1, lbe1, lm1, lv1, lw2, lb2, lg2, lbe2, lm2, lv2,
        wsf, w1f, w2f);
    gpath_kernel<<<8, 256, 0, stream>>>(
        gw1, gb1, gg1, gbe1, gm1, gv1, gw2, gb2, gg2, gbe2, gm2, gv2, wsf);
    main_kernel<<<2048, 256, 0, stream>>>(x1, x2, x3, wsf, w1f, w2f, (float*)d_out);
}